// Round 4
// baseline (1886.386 us; speedup 1.0000x reference)
//
#include <hip/hip_runtime.h>
#include <hip/hip_bf16.h>

typedef __bf16 bf16x8 __attribute__((ext_vector_type(8)));
typedef float floatx4 __attribute__((ext_vector_type(4)));

#define DEV __device__ __forceinline__

DEV float gelu_f(float x) {
    return 0.5f * x * (1.0f + erff(x * 0.70710678118654752f));
}

DEV void block_reduce2(float& a, float& b, float* s) {
    #pragma unroll
    for (int o = 32; o > 0; o >>= 1) {
        a += __shfl_down(a, o, 64);
        b += __shfl_down(b, o, 64);
    }
    __syncthreads();
    int wv = threadIdx.x >> 6;
    if ((threadIdx.x & 63) == 0) { s[wv * 2] = a; s[wv * 2 + 1] = b; }
    __syncthreads();
    int nw = blockDim.x >> 6;
    float ra = 0.f, rb = 0.f;
    for (int i = 0; i < nw; ++i) { ra += s[i * 2]; rb += s[i * 2 + 1]; }
    a = ra; b = rb;
}

// ---------------------------------------------------------------- lb: softmax over depth, cumsum, minus first
__global__ __launch_bounds__(256) void compute_lb(const float* __restrict__ lbin, float* __restrict__ lbout) {
    int d = blockIdx.x * 256 + threadIdx.x;
    if (d >= 768) return;
    float v[8];
    float mx = -1e30f;
    #pragma unroll
    for (int i = 0; i < 8; ++i) { v[i] = lbin[i * 768 + d]; mx = fmaxf(mx, v[i]); }
    float s = 0.f;
    #pragma unroll
    for (int i = 0; i < 8; ++i) { v[i] = expf(v[i] - mx); s += v[i]; }
    float inv = 1.f / s;
    float first = v[0] * inv;
    float cum = 0.f;
    #pragma unroll
    for (int i = 0; i < 8; ++i) { cum += v[i] * inv; lbout[i * 768 + d] = cum - first; }
}

// ---------------------------------------------------------------- x init: cls row = cls+pos[0]; token rows = spt_b+pos[1+p]
__global__ __launch_bounds__(256) void init_tokens(const float* __restrict__ cls, const float* __restrict__ pos,
                                                   const float* __restrict__ bias, float* __restrict__ x) {
    int i = blockIdx.x * 256 + threadIdx.x;       // 16*257*768 = 3157248
    if (i >= 16 * 257 * 768) return;
    int d = i % 768;
    int row = i / 768;                             // b*257 + t
    int t = row % 257;
    float v;
    if (t == 0) v = cls[d] + pos[d];
    else        v = bias[d] + pos[(size_t)t * 768 + d];
    x[(size_t)row * 768 + d] = v;
}

// ---------------------------------------------------------------- patch gather + layernorm -> bf16 [4096 x 3840]
__global__ __launch_bounds__(256) void patch_ln(const float* __restrict__ img, const float* __restrict__ g,
                                                const float* __restrict__ bt, __hip_bfloat16* __restrict__ out) {
    int pm = blockIdx.x;              // 0..4095   = b*256 + (ph*16+pw)
    int b = pm >> 8, pp = pm & 255;
    int ph = pp >> 4, pw = pp & 15;
    __shared__ float pv[3840];
    __shared__ float sbuf[8];
    float s = 0.f, ss = 0.f;
    #pragma unroll
    for (int i = 0; i < 15; ++i) {
        int f = threadIdx.x + i * 256;
        int pi = f / 15, cc = f % 15;
        int ip = pi >> 4, jp = pi & 15;
        int g5 = cc / 3, ch = cc % 3;
        int sh = (g5 == 3) - (g5 == 4);       // groups: 0:(0,0) 1:(0,1) 2:(0,-1) 3:(1,0) 4:(-1,0)
        int sw = (g5 == 1) - (g5 == 2);
        int y = ph * 16 + ip - sh;
        int x = pw * 16 + jp - sw;
        float val = 0.f;
        if ((unsigned)y < 256u && (unsigned)x < 256u)
            val = img[(((size_t)b * 3 + ch) * 256 + y) * 256 + x];
        pv[f] = val; s += val; ss += val * val;
    }
    block_reduce2(s, ss, sbuf);
    float mean = s * (1.f / 3840.f);
    float var  = ss * (1.f / 3840.f) - mean * mean;
    float inv  = rsqrtf(var + 1e-5f);
    #pragma unroll
    for (int i = 0; i < 15; ++i) {
        int f = threadIdx.x + i * 256;
        out[(size_t)pm * 3840 + f] = __float2bfloat16((pv[f] - mean) * inv * g[f] + bt[f]);
    }
}

// ---------------------------------------------------------------- fp32 [K,N] -> bf16 [N,K] tiled transpose-cast
__global__ __launch_bounds__(256) void transpose_cast(const float* __restrict__ W, __hip_bfloat16* __restrict__ Wt,
                                                      int K, int N) {
    __shared__ float tile[32][33];
    int k0 = blockIdx.x * 32, n0 = blockIdx.y * 32;
    int tx = threadIdx.x & 31, ty = threadIdx.x >> 5;   // ty 0..7
    #pragma unroll
    for (int i = 0; i < 4; ++i) {
        int k = ty + i * 8;
        tile[k][tx] = W[(size_t)(k0 + k) * N + n0 + tx];
    }
    __syncthreads();
    #pragma unroll
    for (int i = 0; i < 4; ++i) {
        int n = ty + i * 8;
        Wt[(size_t)(n0 + n) * K + k0 + tx] = __float2bfloat16(tile[tx][n]);
    }
}

// ---------------------------------------------------------------- rmsnorm fp32 -> bf16, row = 768
__global__ __launch_bounds__(256) void rmsnorm_kernel(const float* __restrict__ x, __hip_bfloat16* __restrict__ out) {
    int row = blockIdx.x;
    const float* xr = x + (size_t)row * 768;
    __shared__ float sbuf[8];
    float v[3];
    float ss = 0.f, d0 = 0.f;
    #pragma unroll
    for (int i = 0; i < 3; ++i) { v[i] = xr[threadIdx.x + i * 256]; ss += v[i] * v[i]; }
    block_reduce2(ss, d0, sbuf);
    float scale = rsqrtf(ss * (1.f / 768.f) + 1e-6f);
    #pragma unroll
    for (int i = 0; i < 3; ++i)
        out[(size_t)row * 768 + threadIdx.x + i * 256] = __float2bfloat16(v[i] * scale);
}

// ---------------------------------------------------------------- hgru2 scan over BATCH axis (N=16), per (t,h)
__global__ __launch_bounds__(256) void hgru_scan(const float* __restrict__ feat, __hip_bfloat16* __restrict__ o) {
    int idx = blockIdx.x * 256 + threadIdx.x;
    if (idx >= 257 * 384) return;
    int t = idx / 384, h = idx % 384;
    float2 V[16], Q[16], L[16];
    #pragma unroll
    for (int n = 0; n < 16; ++n) {
        size_t base = ((size_t)n * 257 + t) * 2304 + h * 2;
        V[n] = *(const float2*)(feat + base);
        Q[n] = *(const float2*)(feat + base + 768);
        L[n] = *(const float2*)(feat + base + 1536);
    }
    float S00 = 0.f, S01 = 0.f, S10 = 0.f, S11 = 0.f;
    #pragma unroll
    for (int n = 0; n < 16; ++n) {
        float l0 = L[n].x, l1 = L[n].y;
        float k0 = 1.f - l0, k1 = 1.f - l1;
        S00 = l0 * S00 + k0 * V[n].x; S01 = l0 * S01 + k0 * V[n].y;
        S10 = l1 * S10 + k1 * V[n].x; S11 = l1 * S11 + k1 * V[n].y;
        float o0 = Q[n].x * S00 + Q[n].y * S10;
        float o1 = Q[n].x * S01 + Q[n].y * S11;
        __hip_bfloat162 ov;
        ov.x = __float2bfloat16(o0);
        ov.y = __float2bfloat16(o1);
        *(__hip_bfloat162*)(o + ((size_t)n * 257 + t) * 768 + h * 2) = ov;
    }
}

// ---------------------------------------------------------------- final: rmsnorm + layernorm + head GEMM (tiny)
__global__ __launch_bounds__(256) void head_kernel(const float* __restrict__ x, const float* __restrict__ g,
                                                   const float* __restrict__ be, const float* __restrict__ hw,
                                                   const float* __restrict__ hb, float* __restrict__ out) {
    int b = blockIdx.x;
    const float* xr = x + (size_t)b * 257 * 768;
    __shared__ float z[768];
    __shared__ float sbuf[8];
    float v[3];
    float ss = 0.f, d0 = 0.f;
    #pragma unroll
    for (int i = 0; i < 3; ++i) { v[i] = xr[threadIdx.x + i * 256]; ss += v[i] * v[i]; }
    block_reduce2(ss, d0, sbuf);
    float rs = rsqrtf(ss * (1.f / 768.f) + 1e-6f);
    float s = 0.f, s2 = 0.f;
    #pragma unroll
    for (int i = 0; i < 3; ++i) { float y = v[i] * rs; s += y; s2 += y * y; }
    block_reduce2(s, s2, sbuf);
    float mean = s * (1.f / 768.f);
    float var  = s2 * (1.f / 768.f) - mean * mean;
    float inv  = rsqrtf(var + 1e-5f);
    #pragma unroll
    for (int i = 0; i < 3; ++i) {
        int d = threadIdx.x + i * 256;
        z[d] = (v[i] * rs - mean) * inv * g[d] + be[d];
    }
    __syncthreads();
    int j = blockIdx.y * 256 + threadIdx.x;
    if (j < 1000) {
        float acc = hb[j];
        for (int d = 0; d < 768; ++d) acc += z[d] * hw[d * 1000 + j];
        out[b * 1000 + j] = acc;
    }
}

// ---------------------------------------------------------------- bf16 MFMA GEMM: C[M,N] = A[M,K] @ Bt[N,K]^T
// BM=128 x BN(64|128), BK=32, 4 waves (2x2), DEPTH-deep LDS ring with counted vmcnt.
// T2 slot-swizzle (rule #21: both-sides-or-neither): global_load_lds dest stays LINEAR;
//   the global SOURCE 16B-slot within each row's 64B is permuted slot^=((row&15)>>1)&3
//   (involution, same 64B footprint -> coalescing unchanged), and ds_read applies the
//   same XOR. Per 16-lane phase this turns the 8-way row-stride-64B bank conflict into
//   2-way (free, m136).
// DEPTH=4 for BN=64 (LPS=3 loads/stage -> steady vmcnt(6), 3 iters of slack ~ full HBM
//   latency; LDS 48KB -> 3 blocks/CU). DEPTH=3 for BN=128 (48KB; depth-4 would drop
//   residency 3->2, m132 lesson).
// No split-K anywhere (round-1 lesson: fp32 atomic RMW was the bottleneck).
// EPI: 1=hgru feat (gelu/gelu/lambda)  3=bias+gelu->bf16
//      6=non-atomic residual accumulate (+ optional bias)   7=patch-embed accumulate (row remap)
template<int EPI, int BN, int DEPTH>
__global__ __launch_bounds__(256) void gemm_bt(
        const __hip_bfloat16* __restrict__ A, const __hip_bfloat16* __restrict__ Bt,
        int N, int Ktot, int Mvalid,
        float* __restrict__ outf, __hip_bfloat16* __restrict__ outb,
        const float* __restrict__ bias, const float* __restrict__ aux) {
    constexpr int WNF = BN / 32;                      // B frags per wave
    __shared__ alignas(16) __hip_bfloat16 Als[DEPTH][128 * 32];
    __shared__ alignas(16) __hip_bfloat16 Bls[DEPTH][BN * 32];
    const int tid  = threadIdx.x;
    const int lane = tid & 63;
    const int wv   = tid >> 6;

    // T1: bijective XCD-aware remap (m204)
    const int gx = gridDim.x;
    const int nwg = gx * gridDim.y;
    const int orig = blockIdx.x + gx * blockIdx.y;
    const int q = nwg >> 3, r = nwg & 7;
    const int xcd = orig & 7, off = orig >> 3;
    const int wg = (xcd < r ? xcd * (q + 1) : r * (q + 1) + (xcd - r) * q) + off;
    const int n0 = (wg % gx) * BN;
    const int m0 = (wg / gx) * 128;

    const int wm = wv & 1, wn = wv >> 1;
    const int fr = lane & 15;
    const int fq = lane >> 4;
    const int srow = lane >> 2;                         // 0..15 local row staged by this lane
    const int ssw  = (((lane & 3) ^ ((srow >> 1) & 3)) * 8);  // swizzled source slot (elems)
    const int rsw  = ((fq ^ ((fr >> 1) & 3)) * 8);            // swizzled read slot (elems)

    floatx4 acc[4][WNF];
    #pragma unroll
    for (int mi = 0; mi < 4; ++mi)
        #pragma unroll
        for (int ni = 0; ni < WNF; ++ni)
            acc[mi][ni] = (floatx4){0.f, 0.f, 0.f, 0.f};

    // Per-thread loads per stage: A 2 + B BN/64  (BN=128 -> 4, BN=64 -> 3).
    auto stage = [&](int kt, int buf) {
        #pragma unroll
        for (int j = 0; j < 2; ++j) {
            int cc = wv * 2 + j;
            const __hip_bfloat16* ga = A + (size_t)(m0 + cc * 16 + srow) * Ktot + kt + ssw;
            __builtin_amdgcn_global_load_lds((const __attribute__((address_space(1))) void*)ga,
                                             (__attribute__((address_space(3))) void*)(&Als[buf][cc * 512]), 16, 0, 0);
        }
        #pragma unroll
        for (int j = 0; j < BN / 64; ++j) {
            int cc = wv * (BN / 64) + j;
            const __hip_bfloat16* gb = Bt + (size_t)(n0 + cc * 16 + srow) * Ktot + kt + ssw;
            __builtin_amdgcn_global_load_lds((const __attribute__((address_space(1))) void*)gb,
                                             (__attribute__((address_space(3))) void*)(&Bls[buf][cc * 512]), 16, 0, 0);
        }
    };

    const int nk = Ktot / 32;             // >= 24 for all shapes here
    #pragma unroll
    for (int t = 0; t < DEPTH - 1; ++t) stage(t * 32, t);

    int cur = 0;
    for (int i = 0; i < nk; ++i) {
        // Wait only for OWN tile-i loads; deeper tiles stay in flight across the barrier.
        if constexpr (DEPTH == 4) {           // BN=64, LPS=3
            if (i + 2 < nk)      asm volatile("s_waitcnt vmcnt(6)" ::: "memory");
            else if (i + 1 < nk) asm volatile("s_waitcnt vmcnt(3)" ::: "memory");
            else                 asm volatile("s_waitcnt vmcnt(0)" ::: "memory");
        } else {                              // DEPTH=3
            if (i + 1 < nk) {
                if constexpr (BN == 128) asm volatile("s_waitcnt vmcnt(4)" ::: "memory");
                else                     asm volatile("s_waitcnt vmcnt(3)" ::: "memory");
            } else {
                asm volatile("s_waitcnt vmcnt(0)" ::: "memory");
            }
        }
        __builtin_amdgcn_s_barrier();          // buf i fully staged, buf (i-1) fully consumed
        __builtin_amdgcn_sched_barrier(0);     // pin ds_reads/stages below the barrier

        bf16x8 af[4], bfv[WNF];
        #pragma unroll
        for (int mi = 0; mi < 4; ++mi)
            af[mi] = *(const bf16x8*)((const void*)&Als[cur][(wm * 64 + mi * 16 + fr) * 32 + rsw]);
        #pragma unroll
        for (int ni = 0; ni < WNF; ++ni)
            bfv[ni] = *(const bf16x8*)((const void*)&Bls[cur][(wn * (BN / 2) + ni * 16 + fr) * 32 + rsw]);

        if (i + DEPTH - 1 < nk) stage((i + DEPTH - 1) * 32, cur == 0 ? DEPTH - 1 : cur - 1);

        #pragma unroll
        for (int mi = 0; mi < 4; ++mi)
            #pragma unroll
            for (int ni = 0; ni < WNF; ++ni)
                acc[mi][ni] = __builtin_amdgcn_mfma_f32_16x16x32_bf16(af[mi], bfv[ni], acc[mi][ni], 0, 0, 0);

        cur = (cur == DEPTH - 1) ? 0 : cur + 1;
    }

    // C/D layout: col = lane&15, row = (lane>>4)*4 + reg  [m89/m91-verified]
    const int cr0 = wm * 64 + fq * 4;
    const int cc0 = wn * (BN / 2) + fr;
    #pragma unroll
    for (int mi = 0; mi < 4; ++mi) {
        #pragma unroll
        for (int rr = 0; rr < 4; ++rr) {
            int gm = m0 + cr0 + mi * 16 + rr;
            if (gm >= Mvalid) continue;
            #pragma unroll
            for (int ni = 0; ni < WNF; ++ni) {
                int gn = n0 + cc0 + ni * 16;
                float v = acc[mi][ni][rr];
                if (EPI == 1) {
                    float res;
                    if (gn < 1536) {
                        res = gelu_f(v);
                    } else {
                        float l = aux[gn - 1536];
                        res = l + (1.f - l) / (1.f + expf(-v));
                    }
                    outf[(size_t)gm * N + gn] = res;
                } else if (EPI == 3) {
                    outb[(size_t)gm * N + gn] = __float2bfloat16(gelu_f(v + bias[gn]));
                } else if (EPI == 6) {
                    float add = v + (bias ? bias[gn] : 0.f);
                    outf[(size_t)gm * N + gn] += add;       // exactly one owner per (gm,gn): no atomics
                } else if (EPI == 7) {
                    size_t orow = (size_t)(gm >> 8) * 257 + 1 + (gm & 255);
                    outf[orow * 768 + gn] += v;             // xbuf pre-initialized with bias+pos
                }
            }
        }
    }
}

// ----------------------------------------------------------------
extern "C" void kernel_launch(void* const* d_in, const int* in_sizes, int n_in,
                              void* d_out, int out_size, void* d_ws, size_t ws_size,
                              hipStream_t stream) {
    const float* img        = (const float*)d_in[0];
    const float* spt_ln_g   = (const float*)d_in[1];
    const float* spt_ln_b   = (const float*)d_in[2];
    const float* spt_w      = (const float*)d_in[3];
    const float* spt_b      = (const float*)d_in[4];
    const float* pos_emb    = (const float*)d_in[5];
    const float* cls_token  = (const float*)d_in[6];
    const float* lower_bnds = (const float*)d_in[7];
    const float* in_proj_w  = (const float*)d_in[8];
    const float* out_proj_w = (const float*)d_in[9];
    const float* ff_w1      = (const float*)d_in[10];
    const float* ff_b1      = (const float*)d_in[11];
    const float* ff_w2      = (const float*)d_in[12];
    const float* ff_b2      = (const float*)d_in[13];
    const float* head_ln_g  = (const float*)d_in[14];
    const float* head_ln_b  = (const float*)d_in[15];
    const float* head_w     = (const float*)d_in[16];
    const float* head_b     = (const float*)d_in[17];
    float* out = (float*)d_out;

    // ---- workspace bump allocator (256B aligned). Total ~135 MB.
    char* wp = (char*)d_ws;
    auto alloc = [&](size_t bytes) -> void* {
        void* p = (void*)wp;
        wp += (bytes + 255) & ~(size_t)255;
        return p;
    };
    float*          lbbuf   = (float*)         alloc(8 * 768 * 4);
    __hip_bfloat16* patches = (__hip_bfloat16*)alloc((size_t)4096 * 3840 * 2);
    __hip_bfloat16* spt_wt  = (__hip_bfloat16*)alloc((size_t)768 * 3840 * 2);
    float*          xbuf    = (float*)         alloc((size_t)4112 * 768 * 4);
    __hip_bfloat16* normbuf = (__hip_bfloat16*)alloc((size_t)4224 * 768 * 2);   // padded M
    float*          featbuf = (float*)         alloc((size_t)4112 * 2304 * 4);
    __hip_bfloat16* obuf    = (__hip_bfloat16*)alloc((size_t)4224 * 768 * 2);   // padded M
    __hip_bfloat16* midbuf  = (__hip_bfloat16*)alloc((size_t)4224 * 3072 * 2);  // padded M
    __hip_bfloat16* w_in_t  = (__hip_bfloat16*)alloc((size_t)2304 * 768 * 2);
    __hip_bfloat16* w_out_t = (__hip_bfloat16*)alloc((size_t)768 * 768 * 2);
    __hip_bfloat16* w1_t    = (__hip_bfloat16*)alloc((size_t)3072 * 768 * 2);
    __hip_bfloat16* w2_t    = (__hip_bfloat16*)alloc((size_t)768 * 3072 * 2);
    (void)in_sizes; (void)n_in; (void)out_size; (void)ws_size;

    // ---- prologue
    compute_lb<<<3, 256, 0, stream>>>(lower_bnds, lbbuf);
    init_tokens<<<(16 * 257 * 768 + 255) / 256, 256, 0, stream>>>(cls_token, pos_emb, spt_b, xbuf);
    patch_ln<<<4096, 256, 0, stream>>>(img, spt_ln_g, spt_ln_b, patches);
    transpose_cast<<<dim3(3840 / 32, 768 / 32), 256, 0, stream>>>(spt_w, spt_wt, 3840, 768);
    // x rows (b*257+1+p) += LN(patches) @ spt_w   (bias+pos already in xbuf); BN=64, no split-K
    gemm_bt<7, 64, 4><<<dim3(12, 32), 256, 0, stream>>>(patches, spt_wt, 768, 3840, 4096,
                                                        xbuf, nullptr, nullptr, nullptr);

    // ---- layers
    for (int i = 0; i < 8; ++i) {
        rmsnorm_kernel<<<4112, 256, 0, stream>>>(xbuf, normbuf);
        transpose_cast<<<dim3(24, 72), 256, 0, stream>>>(in_proj_w + (size_t)i * 768 * 2304, w_in_t, 768, 2304);
        gemm_bt<1, 128, 3><<<dim3(18, 33), 256, 0, stream>>>(normbuf, w_in_t, 2304, 768, 4112,
                                                             featbuf, nullptr, nullptr, lbbuf + i * 768);
        hgru_scan<<<386, 256, 0, stream>>>(featbuf, obuf);
        transpose_cast<<<dim3(24, 24), 256, 0, stream>>>(out_proj_w + (size_t)i * 768 * 768, w_out_t, 768, 768);
        gemm_bt<6, 64, 4><<<dim3(12, 33), 256, 0, stream>>>(obuf, w_out_t, 768, 768, 4112,
                                                            xbuf, nullptr, nullptr, nullptr);
        rmsnorm_kernel<<<4112, 256, 0, stream>>>(xbuf, normbuf);
        transpose_cast<<<dim3(24, 96), 256, 0, stream>>>(ff_w1 + (size_t)i * 768 * 3072, w1_t, 768, 3072);
        gemm_bt<3, 128, 3><<<dim3(24, 33), 256, 0, stream>>>(normbuf, w1_t, 3072, 768, 4112,
                                                             nullptr, midbuf, ff_b1 + i * 3072, nullptr);
        transpose_cast<<<dim3(96, 24), 256, 0, stream>>>(ff_w2 + (size_t)i * 3072 * 768, w2_t, 3072, 768);
        gemm_bt<6, 64, 4><<<dim3(12, 33), 256, 0, stream>>>(midbuf, w2_t, 768, 3072, 4112,
                                                            xbuf, nullptr, ff_b2 + i * 768, nullptr);
    }

    // ---- head
    head_kernel<<<dim3(16, 4), 256, 0, stream>>>(xbuf, head_ln_g, head_ln_b, head_w, head_b, out);
}

// Round 5
// 1778.232 us; speedup vs baseline: 1.0608x; 1.0608x over previous
//
#include <hip/hip_runtime.h>
#include <hip/hip_bf16.h>

typedef __bf16 bf16x8 __attribute__((ext_vector_type(8)));
typedef float floatx4 __attribute__((ext_vector_type(4)));

#define DEV __device__ __forceinline__

DEV float gelu_f(float x) {
    return 0.5f * x * (1.0f + erff(x * 0.70710678118654752f));
}

DEV void block_reduce2(float& a, float& b, float* s) {
    #pragma unroll
    for (int o = 32; o > 0; o >>= 1) {
        a += __shfl_down(a, o, 64);
        b += __shfl_down(b, o, 64);
    }
    __syncthreads();
    int wv = threadIdx.x >> 6;
    if ((threadIdx.x & 63) == 0) { s[wv * 2] = a; s[wv * 2 + 1] = b; }
    __syncthreads();
    int nw = blockDim.x >> 6;
    float ra = 0.f, rb = 0.f;
    for (int i = 0; i < nw; ++i) { ra += s[i * 2]; rb += s[i * 2 + 1]; }
    a = ra; b = rb;
}

// ---------------------------------------------------------------- lb: softmax over depth, cumsum, minus first
__global__ __launch_bounds__(256) void compute_lb(const float* __restrict__ lbin, float* __restrict__ lbout) {
    int d = blockIdx.x * 256 + threadIdx.x;
    if (d >= 768) return;
    float v[8];
    float mx = -1e30f;
    #pragma unroll
    for (int i = 0; i < 8; ++i) { v[i] = lbin[i * 768 + d]; mx = fmaxf(mx, v[i]); }
    float s = 0.f;
    #pragma unroll
    for (int i = 0; i < 8; ++i) { v[i] = expf(v[i] - mx); s += v[i]; }
    float inv = 1.f / s;
    float first = v[0] * inv;
    float cum = 0.f;
    #pragma unroll
    for (int i = 0; i < 8; ++i) { cum += v[i] * inv; lbout[i * 768 + d] = cum - first; }
}

// ---------------------------------------------------------------- x init: cls row = cls+pos[0]; token rows = spt_b+pos[1+p]
__global__ __launch_bounds__(256) void init_tokens(const float* __restrict__ cls, const float* __restrict__ pos,
                                                   const float* __restrict__ bias, float* __restrict__ x) {
    int i = blockIdx.x * 256 + threadIdx.x;       // 16*257*768 = 3157248
    if (i >= 16 * 257 * 768) return;
    int d = i % 768;
    int row = i / 768;                             // b*257 + t
    int t = row % 257;
    float v;
    if (t == 0) v = cls[d] + pos[d];
    else        v = bias[d] + pos[(size_t)t * 768 + d];
    x[(size_t)row * 768 + d] = v;
}

// ---------------------------------------------------------------- patch gather + layernorm -> bf16 [4096 x 3840]
__global__ __launch_bounds__(256) void patch_ln(const float* __restrict__ img, const float* __restrict__ g,
                                                const float* __restrict__ bt, __hip_bfloat16* __restrict__ out) {
    int pm = blockIdx.x;              // 0..4095   = b*256 + (ph*16+pw)
    int b = pm >> 8, pp = pm & 255;
    int ph = pp >> 4, pw = pp & 15;
    __shared__ float pv[3840];
    __shared__ float sbuf[8];
    float s = 0.f, ss = 0.f;
    #pragma unroll
    for (int i = 0; i < 15; ++i) {
        int f = threadIdx.x + i * 256;
        int pi = f / 15, cc = f % 15;
        int ip = pi >> 4, jp = pi & 15;
        int g5 = cc / 3, ch = cc % 3;
        int sh = (g5 == 3) - (g5 == 4);       // groups: 0:(0,0) 1:(0,1) 2:(0,-1) 3:(1,0) 4:(-1,0)
        int sw = (g5 == 1) - (g5 == 2);
        int y = ph * 16 + ip - sh;
        int x = pw * 16 + jp - sw;
        float val = 0.f;
        if ((unsigned)y < 256u && (unsigned)x < 256u)
            val = img[(((size_t)b * 3 + ch) * 256 + y) * 256 + x];
        pv[f] = val; s += val; ss += val * val;
    }
    block_reduce2(s, ss, sbuf);
    float mean = s * (1.f / 3840.f);
    float var  = ss * (1.f / 3840.f) - mean * mean;
    float inv  = rsqrtf(var + 1e-5f);
    #pragma unroll
    for (int i = 0; i < 15; ++i) {
        int f = threadIdx.x + i * 256;
        out[(size_t)pm * 3840 + f] = __float2bfloat16((pv[f] - mean) * inv * g[f] + bt[f]);
    }
}

// ---------------------------------------------------------------- fp32 [K,N] -> bf16 [N,K] tiled transpose-cast
__global__ __launch_bounds__(256) void transpose_cast(const float* __restrict__ W, __hip_bfloat16* __restrict__ Wt,
                                                      int K, int N) {
    __shared__ float tile[32][33];
    int k0 = blockIdx.x * 32, n0 = blockIdx.y * 32;
    int tx = threadIdx.x & 31, ty = threadIdx.x >> 5;   // ty 0..7
    #pragma unroll
    for (int i = 0; i < 4; ++i) {
        int k = ty + i * 8;
        tile[k][tx] = W[(size_t)(k0 + k) * N + n0 + tx];
    }
    __syncthreads();
    #pragma unroll
    for (int i = 0; i < 4; ++i) {
        int n = ty + i * 8;
        Wt[(size_t)(n0 + n) * K + k0 + tx] = __float2bfloat16(tile[tx][n]);
    }
}

// ---------------------------------------------------------------- rmsnorm fp32 -> bf16, row = 768
__global__ __launch_bounds__(256) void rmsnorm_kernel(const float* __restrict__ x, __hip_bfloat16* __restrict__ out) {
    int row = blockIdx.x;
    const float* xr = x + (size_t)row * 768;
    __shared__ float sbuf[8];
    float v[3];
    float ss = 0.f, d0 = 0.f;
    #pragma unroll
    for (int i = 0; i < 3; ++i) { v[i] = xr[threadIdx.x + i * 256]; ss += v[i] * v[i]; }
    block_reduce2(ss, d0, sbuf);
    float scale = rsqrtf(ss * (1.f / 768.f) + 1e-6f);
    #pragma unroll
    for (int i = 0; i < 3; ++i)
        out[(size_t)row * 768 + threadIdx.x + i * 256] = __float2bfloat16(v[i] * scale);
}

// ---------------------------------------------------------------- hgru2 scan over BATCH axis (N=16), per (t,h)
__global__ __launch_bounds__(256) void hgru_scan(const float* __restrict__ feat, __hip_bfloat16* __restrict__ o) {
    int idx = blockIdx.x * 256 + threadIdx.x;
    if (idx >= 257 * 384) return;
    int t = idx / 384, h = idx % 384;
    float2 V[16], Q[16], L[16];
    #pragma unroll
    for (int n = 0; n < 16; ++n) {
        size_t base = ((size_t)n * 257 + t) * 2304 + h * 2;
        V[n] = *(const float2*)(feat + base);
        Q[n] = *(const float2*)(feat + base + 768);
        L[n] = *(const float2*)(feat + base + 1536);
    }
    float S00 = 0.f, S01 = 0.f, S10 = 0.f, S11 = 0.f;
    #pragma unroll
    for (int n = 0; n < 16; ++n) {
        float l0 = L[n].x, l1 = L[n].y;
        float k0 = 1.f - l0, k1 = 1.f - l1;
        S00 = l0 * S00 + k0 * V[n].x; S01 = l0 * S01 + k0 * V[n].y;
        S10 = l1 * S10 + k1 * V[n].x; S11 = l1 * S11 + k1 * V[n].y;
        float o0 = Q[n].x * S00 + Q[n].y * S10;
        float o1 = Q[n].x * S01 + Q[n].y * S11;
        __hip_bfloat162 ov;
        ov.x = __float2bfloat16(o0);
        ov.y = __float2bfloat16(o1);
        *(__hip_bfloat162*)(o + ((size_t)n * 257 + t) * 768 + h * 2) = ov;
    }
}

// ---------------------------------------------------------------- final: rmsnorm + layernorm + head GEMM (tiny)
__global__ __launch_bounds__(256) void head_kernel(const float* __restrict__ x, const float* __restrict__ g,
                                                   const float* __restrict__ be, const float* __restrict__ hw,
                                                   const float* __restrict__ hb, float* __restrict__ out) {
    int b = blockIdx.x;
    const float* xr = x + (size_t)b * 257 * 768;
    __shared__ float z[768];
    __shared__ float sbuf[8];
    float v[3];
    float ss = 0.f, d0 = 0.f;
    #pragma unroll
    for (int i = 0; i < 3; ++i) { v[i] = xr[threadIdx.x + i * 256]; ss += v[i] * v[i]; }
    block_reduce2(ss, d0, sbuf);
    float rs = rsqrtf(ss * (1.f / 768.f) + 1e-6f);
    float s = 0.f, s2 = 0.f;
    #pragma unroll
    for (int i = 0; i < 3; ++i) { float y = v[i] * rs; s += y; s2 += y * y; }
    block_reduce2(s, s2, sbuf);
    float mean = s * (1.f / 768.f);
    float var  = s2 * (1.f / 768.f) - mean * mean;
    float inv  = rsqrtf(var + 1e-5f);
    #pragma unroll
    for (int i = 0; i < 3; ++i) {
        int d = threadIdx.x + i * 256;
        z[d] = (v[i] * rs - mean) * inv * g[d] + be[d];
    }
    __syncthreads();
    int j = blockIdx.y * 256 + threadIdx.x;
    if (j < 1000) {
        float acc = hb[j];
        for (int d = 0; d < 768; ++d) acc += z[d] * hw[d * 1000 + j];
        out[b * 1000 + j] = acc;
    }
}

// ---------------------------------------------------------------- CONTROL: bf16 MFMA GEMM, BK=32 (unchanged from R4)
// BM=128 x BN=128, BK=32, 4 waves (2x2), DEPTH=3 LDS ring with counted vmcnt.
// EPI: 1=hgru feat (gelu/gelu/lambda)  3=bias+gelu->bf16
template<int EPI, int BN, int DEPTH>
__global__ __launch_bounds__(256) void gemm_bt(
        const __hip_bfloat16* __restrict__ A, const __hip_bfloat16* __restrict__ Bt,
        int N, int Ktot, int Mvalid,
        float* __restrict__ outf, __hip_bfloat16* __restrict__ outb,
        const float* __restrict__ bias, const float* __restrict__ aux) {
    constexpr int WNF = BN / 32;                      // B frags per wave
    __shared__ alignas(16) __hip_bfloat16 Als[DEPTH][128 * 32];
    __shared__ alignas(16) __hip_bfloat16 Bls[DEPTH][BN * 32];
    const int tid  = threadIdx.x;
    const int lane = tid & 63;
    const int wv   = tid >> 6;

    // T1: bijective XCD-aware remap (m204)
    const int gx = gridDim.x;
    const int nwg = gx * gridDim.y;
    const int orig = blockIdx.x + gx * blockIdx.y;
    const int q = nwg >> 3, r = nwg & 7;
    const int xcd = orig & 7, off = orig >> 3;
    const int wg = (xcd < r ? xcd * (q + 1) : r * (q + 1) + (xcd - r) * q) + off;
    const int n0 = (wg % gx) * BN;
    const int m0 = (wg / gx) * 128;

    const int wm = wv & 1, wn = wv >> 1;
    const int fr = lane & 15;
    const int fq = lane >> 4;
    const int srow = lane >> 2;                         // 0..15 local row staged by this lane
    const int ssw  = (((lane & 3) ^ ((srow >> 1) & 3)) * 8);  // swizzled source slot (elems)
    const int rsw  = ((fq ^ ((fr >> 1) & 3)) * 8);            // swizzled read slot (elems)

    floatx4 acc[4][WNF];
    #pragma unroll
    for (int mi = 0; mi < 4; ++mi)
        #pragma unroll
        for (int ni = 0; ni < WNF; ++ni)
            acc[mi][ni] = (floatx4){0.f, 0.f, 0.f, 0.f};

    auto stage = [&](int kt, int buf) {
        #pragma unroll
        for (int j = 0; j < 2; ++j) {
            int cc = wv * 2 + j;
            const __hip_bfloat16* ga = A + (size_t)(m0 + cc * 16 + srow) * Ktot + kt + ssw;
            __builtin_amdgcn_global_load_lds((const __attribute__((address_space(1))) void*)ga,
                                             (__attribute__((address_space(3))) void*)(&Als[buf][cc * 512]), 16, 0, 0);
        }
        #pragma unroll
        for (int j = 0; j < BN / 64; ++j) {
            int cc = wv * (BN / 64) + j;
            const __hip_bfloat16* gb = Bt + (size_t)(n0 + cc * 16 + srow) * Ktot + kt + ssw;
            __builtin_amdgcn_global_load_lds((const __attribute__((address_space(1))) void*)gb,
                                             (__attribute__((address_space(3))) void*)(&Bls[buf][cc * 512]), 16, 0, 0);
        }
    };

    const int nk = Ktot / 32;
    #pragma unroll
    for (int t = 0; t < DEPTH - 1; ++t) stage(t * 32, t);

    int cur = 0;
    for (int i = 0; i < nk; ++i) {
        if (i + 1 < nk) {
            if constexpr (BN == 128) asm volatile("s_waitcnt vmcnt(4)" ::: "memory");
            else                     asm volatile("s_waitcnt vmcnt(3)" ::: "memory");
        } else {
            asm volatile("s_waitcnt vmcnt(0)" ::: "memory");
        }
        __builtin_amdgcn_s_barrier();
        __builtin_amdgcn_sched_barrier(0);

        bf16x8 af[4], bfv[WNF];
        #pragma unroll
        for (int mi = 0; mi < 4; ++mi)
            af[mi] = *(const bf16x8*)((const void*)&Als[cur][(wm * 64 + mi * 16 + fr) * 32 + rsw]);
        #pragma unroll
        for (int ni = 0; ni < WNF; ++ni)
            bfv[ni] = *(const bf16x8*)((const void*)&Bls[cur][(wn * (BN / 2) + ni * 16 + fr) * 32 + rsw]);

        if (i + DEPTH - 1 < nk) stage((i + DEPTH - 1) * 32, cur == 0 ? DEPTH - 1 : cur - 1);

        #pragma unroll
        for (int mi = 0; mi < 4; ++mi)
            #pragma unroll
            for (int ni = 0; ni < WNF; ++ni)
                acc[mi][ni] = __builtin_amdgcn_mfma_f32_16x16x32_bf16(af[mi], bfv[ni], acc[mi][ni], 0, 0, 0);

        cur = (cur == DEPTH - 1) ? 0 : cur + 1;
    }

    const int cr0 = wm * 64 + fq * 4;
    const int cc0 = wn * (BN / 2) + fr;
    #pragma unroll
    for (int mi = 0; mi < 4; ++mi) {
        #pragma unroll
        for (int rr = 0; rr < 4; ++rr) {
            int gm = m0 + cr0 + mi * 16 + rr;
            if (gm >= Mvalid) continue;
            #pragma unroll
            for (int ni = 0; ni < WNF; ++ni) {
                int gn = n0 + cc0 + ni * 16;
                float v = acc[mi][ni][rr];
                if (EPI == 1) {
                    float res;
                    if (gn < 1536) {
                        res = gelu_f(v);
                    } else {
                        float l = aux[gn - 1536];
                        res = l + (1.f - l) / (1.f + expf(-v));
                    }
                    outf[(size_t)gm * N + gn] = res;
                } else if (EPI == 3) {
                    outb[(size_t)gm * N + gn] = __float2bfloat16(gelu_f(v + bias[gn]));
                }
            }
        }
    }
}

// ---------------------------------------------------------------- EXPERIMENT: BK=64 GEMM for the BN=64 shapes
// BM=128 x BN=64, BK=64, 4 waves (2x2), DEPTH=3 ring (LDS 72KB -> 2 blocks/CU; these grids
// deliver <=1.55 blocks/CU so no occupancy loss). Halves the phase count vs BK=32: per phase
// 16 MFMA + 12 ds_read + 6 global_load_lds per wave -> per-phase barrier/vmcnt/lgkm overhead
// amortized over 2x the MFMA (H2: round-4 showed a uniform ~127cy/MFMA floor independent of
// occupancy and conflicts -> per-phase fixed cost is the binder).
// LDS rows are 64 bf16 = 128B = exactly 32 banks -> MANDATORY swizzle: slot' = slot ^ (row&7)
// (16B slots, involution; applied on the pre-permuted global source AND the ds_read; the
// global_load_lds destination stays linear — rule #21). Per ds_read_b128 the 64 lanes spread
// uniformly over all 8 slot-columns (8 lanes/column = the 1KB/instr minimum).
// Per-thread global base pointers precomputed once; stage() just adds kt.
// EPI: 6=non-atomic residual accumulate (+ optional bias)   7=patch-embed accumulate (row remap)
template<int EPI>
__global__ __launch_bounds__(256) void gemm64(
        const __hip_bfloat16* __restrict__ A, const __hip_bfloat16* __restrict__ Bt,
        int N, int Ktot, int Mvalid,
        float* __restrict__ outf, const float* __restrict__ bias) {
    __shared__ alignas(16) __hip_bfloat16 Als[3][128 * 64];
    __shared__ alignas(16) __hip_bfloat16 Bls[3][64 * 64];
    const int tid  = threadIdx.x;
    const int lane = tid & 63;
    const int wv   = tid >> 6;

    // T1: bijective XCD-aware remap (m204)
    const int gx = gridDim.x;
    const int nwg = gx * gridDim.y;
    const int orig = blockIdx.x + gx * blockIdx.y;
    const int q = nwg >> 3, r = nwg & 7;
    const int xcd = orig & 7, off = orig >> 3;
    const int wg = (xcd < r ? xcd * (q + 1) : r * (q + 1) + (xcd - r) * q) + off;
    const int n0 = (wg % gx) * 64;
    const int m0 = (wg / gx) * 128;

    const int wm = wv & 1, wn = wv >> 1;      // wave grid 2m x 2n; wave tile 64m x 32n
    const int fr = lane & 15;
    const int fq = lane >> 4;                 // 0..3
    const int srow8 = lane >> 3;              // 0..7  (row within 8-row stage group)
    const int slot8 = lane & 7;               // 0..7  (16B slot within 128B row)
    const int sswz  = (slot8 ^ srow8) * 8;    // swizzled SOURCE elem offset within row

    floatx4 acc[4][2];
    #pragma unroll
    for (int mi = 0; mi < 4; ++mi)
        #pragma unroll
        for (int ni = 0; ni < 2; ++ni)
            acc[mi][ni] = (floatx4){0.f, 0.f, 0.f, 0.f};

    // Per-thread global base pointers (computed once; stage adds kt elems).
    const __hip_bfloat16* pA0 = A  + (size_t)(m0 + wv * 8      + srow8) * Ktot + sswz;
    const __hip_bfloat16* pA1 = A  + (size_t)(m0 + wv * 8 + 32 + srow8) * Ktot + sswz;
    const __hip_bfloat16* pA2 = A  + (size_t)(m0 + wv * 8 + 64 + srow8) * Ktot + sswz;
    const __hip_bfloat16* pA3 = A  + (size_t)(m0 + wv * 8 + 96 + srow8) * Ktot + sswz;
    const __hip_bfloat16* pB0 = Bt + (size_t)(n0 + wv * 8      + srow8) * Ktot + sswz;
    const __hip_bfloat16* pB1 = Bt + (size_t)(n0 + wv * 8 + 32 + srow8) * Ktot + sswz;

    // LDS dest linear per 8-row group: elem = rowbase*64 + lane*8  (= (row)*64 + slot8*8)
    auto stage = [&](int kt, int buf) {
        __hip_bfloat16* la = &Als[buf][(wv * 8) * 64 + lane * 8];
        __hip_bfloat16* lb = &Bls[buf][(wv * 8) * 64 + lane * 8];
        __builtin_amdgcn_global_load_lds((const __attribute__((address_space(1))) void*)(pA0 + kt),
                                         (__attribute__((address_space(3))) void*)(la),            16, 0, 0);
        __builtin_amdgcn_global_load_lds((const __attribute__((address_space(1))) void*)(pA1 + kt),
                                         (__attribute__((address_space(3))) void*)(la + 32 * 64),  16, 0, 0);
        __builtin_amdgcn_global_load_lds((const __attribute__((address_space(1))) void*)(pA2 + kt),
                                         (__attribute__((address_space(3))) void*)(la + 64 * 64),  16, 0, 0);
        __builtin_amdgcn_global_load_lds((const __attribute__((address_space(1))) void*)(pA3 + kt),
                                         (__attribute__((address_space(3))) void*)(la + 96 * 64),  16, 0, 0);
        __builtin_amdgcn_global_load_lds((const __attribute__((address_space(1))) void*)(pB0 + kt),
                                         (__attribute__((address_space(3))) void*)(lb),            16, 0, 0);
        __builtin_amdgcn_global_load_lds((const __attribute__((address_space(1))) void*)(pB1 + kt),
                                         (__attribute__((address_space(3))) void*)(lb + 32 * 64),  16, 0, 0);
    };

    const int nk = Ktot / 64;                 // 12 / 48 / 60 for our shapes
    stage(0, 0);
    stage(64, 1);

    const int rx = fr & 7;                    // read-side swizzle key (row&7)
    int cur = 0;
    for (int i = 0; i < nk; ++i) {
        // Own-tile loads done; next tile's 6 loads stay in flight across the barrier.
        if (i + 1 < nk) asm volatile("s_waitcnt vmcnt(6)" ::: "memory");
        else            asm volatile("s_waitcnt vmcnt(0)" ::: "memory");
        __builtin_amdgcn_s_barrier();
        __builtin_amdgcn_sched_barrier(0);

        bf16x8 af[2][4], bfv[2][2];
        #pragma unroll
        for (int s = 0; s < 2; ++s) {
            int slot = ((s * 4 + fq) ^ rx) * 8;
            #pragma unroll
            for (int mi = 0; mi < 4; ++mi)
                af[s][mi] = *(const bf16x8*)((const void*)&Als[cur][(wm * 64 + mi * 16 + fr) * 64 + slot]);
            #pragma unroll
            for (int ni = 0; ni < 2; ++ni)
                bfv[s][ni] = *(const bf16x8*)((const void*)&Bls[cur][(wn * 32 + ni * 16 + fr) * 64 + slot]);
        }

        if (i + 2 < nk) stage((i + 2) * 64, cur == 0 ? 2 : cur - 1);

        #pragma unroll
        for (int s = 0; s < 2; ++s)
            #pragma unroll
            for (int mi = 0; mi < 4; ++mi)
                #pragma unroll
                for (int ni = 0; ni < 2; ++ni)
                    acc[mi][ni] = __builtin_amdgcn_mfma_f32_16x16x32_bf16(af[s][mi], bfv[s][ni], acc[mi][ni], 0, 0, 0);

        cur = (cur == 2) ? 0 : cur + 1;
    }

    // C/D layout: col = lane&15, row = (lane>>4)*4 + reg  [m89/m91-verified]
    const int cr0 = wm * 64 + fq * 4;
    const int cc0 = wn * 32 + fr;
    #pragma unroll
    for (int mi = 0; mi < 4; ++mi) {
        #pragma unroll
        for (int rr = 0; rr < 4; ++rr) {
            int gm = m0 + cr0 + mi * 16 + rr;
            if (gm >= Mvalid) continue;
            #pragma unroll
            for (int ni = 0; ni < 2; ++ni) {
                int gn = n0 + cc0 + ni * 16;
                float v = acc[mi][ni][rr];
                if (EPI == 6) {
                    float add = v + (bias ? bias[gn] : 0.f);
                    outf[(size_t)gm * N + gn] += add;       // exactly one owner per (gm,gn): no atomics
                } else if (EPI == 7) {
                    size_t orow = (size_t)(gm >> 8) * 257 + 1 + (gm & 255);
                    outf[orow * 768 + gn] += v;             // xbuf pre-initialized with bias+pos
                }
            }
        }
    }
}

// ----------------------------------------------------------------
extern "C" void kernel_launch(void* const* d_in, const int* in_sizes, int n_in,
                              void* d_out, int out_size, void* d_ws, size_t ws_size,
                              hipStream_t stream) {
    const float* img        = (const float*)d_in[0];
    const float* spt_ln_g   = (const float*)d_in[1];
    const float* spt_ln_b   = (const float*)d_in[2];
    const float* spt_w      = (const float*)d_in[3];
    const float* spt_b      = (const float*)d_in[4];
    const float* pos_emb    = (const float*)d_in[5];
    const float* cls_token  = (const float*)d_in[6];
    const float* lower_bnds = (const float*)d_in[7];
    const float* in_proj_w  = (const float*)d_in[8];
    const float* out_proj_w = (const float*)d_in[9];
    const float* ff_w1      = (const float*)d_in[10];
    const float* ff_b1      = (const float*)d_in[11];
    const float* ff_w2      = (const float*)d_in[12];
    const float* ff_b2      = (const float*)d_in[13];
    const float* head_ln_g  = (const float*)d_in[14];
    const float* head_ln_b  = (const float*)d_in[15];
    const float* head_w     = (const float*)d_in[16];
    const float* head_b     = (const float*)d_in[17];
    float* out = (float*)d_out;

    // ---- workspace bump allocator (256B aligned). Total ~135 MB.
    char* wp = (char*)d_ws;
    auto alloc = [&](size_t bytes) -> void* {
        void* p = (void*)wp;
        wp += (bytes + 255) & ~(size_t)255;
        return p;
    };
    float*          lbbuf   = (float*)         alloc(8 * 768 * 4);
    __hip_bfloat16* patches = (__hip_bfloat16*)alloc((size_t)4096 * 3840 * 2);
    __hip_bfloat16* spt_wt  = (__hip_bfloat16*)alloc((size_t)768 * 3840 * 2);
    float*          xbuf    = (float*)         alloc((size_t)4112 * 768 * 4);
    __hip_bfloat16* normbuf = (__hip_bfloat16*)alloc((size_t)4224 * 768 * 2);   // padded M
    float*          featbuf = (float*)         alloc((size_t)4112 * 2304 * 4);
    __hip_bfloat16* obuf    = (__hip_bfloat16*)alloc((size_t)4224 * 768 * 2);   // padded M
    __hip_bfloat16* midbuf  = (__hip_bfloat16*)alloc((size_t)4224 * 3072 * 2);  // padded M
    __hip_bfloat16* w_in_t  = (__hip_bfloat16*)alloc((size_t)2304 * 768 * 2);
    __hip_bfloat16* w_out_t = (__hip_bfloat16*)alloc((size_t)768 * 768 * 2);
    __hip_bfloat16* w1_t    = (__hip_bfloat16*)alloc((size_t)3072 * 768 * 2);
    __hip_bfloat16* w2_t    = (__hip_bfloat16*)alloc((size_t)768 * 3072 * 2);
    (void)in_sizes; (void)n_in; (void)out_size; (void)ws_size;

    // ---- prologue
    compute_lb<<<3, 256, 0, stream>>>(lower_bnds, lbbuf);
    init_tokens<<<(16 * 257 * 768 + 255) / 256, 256, 0, stream>>>(cls_token, pos_emb, spt_b, xbuf);
    patch_ln<<<4096, 256, 0, stream>>>(img, spt_ln_g, spt_ln_b, patches);
    transpose_cast<<<dim3(3840 / 32, 768 / 32), 256, 0, stream>>>(spt_w, spt_wt, 3840, 768);
    // x rows (b*257+1+p) += LN(patches) @ spt_w   (bias+pos already in xbuf); BK=64
    gemm64<7><<<dim3(12, 32), 256, 0, stream>>>(patches, spt_wt, 768, 3840, 4096, xbuf, nullptr);

    // ---- layers
    for (int i = 0; i < 8; ++i) {
        rmsnorm_kernel<<<4112, 256, 0, stream>>>(xbuf, normbuf);
        transpose_cast<<<dim3(24, 72), 256, 0, stream>>>(in_proj_w + (size_t)i * 768 * 2304, w_in_t, 768, 2304);
        gemm_bt<1, 128, 3><<<dim3(18, 33), 256, 0, stream>>>(normbuf, w_in_t, 2304, 768, 4112,
                                                             featbuf, nullptr, nullptr, lbbuf + i * 768);
        hgru_scan<<<386, 256, 0, stream>>>(featbuf, obuf);
        transpose_cast<<<dim3(24, 24), 256, 0, stream>>>(out_proj_w + (size_t)i * 768 * 768, w_out_t, 768, 768);
        gemm64<6><<<dim3(12, 33), 256, 0, stream>>>(obuf, w_out_t, 768, 768, 4112, xbuf, nullptr);
        rmsnorm_kernel<<<4112, 256, 0, stream>>>(xbuf, normbuf);
        transpose_cast<<<dim3(24, 96), 256, 0, stream>>>(ff_w1 + (size_t)i * 768 * 3072, w1_t, 768, 3072);
        gemm_bt<3, 128, 3><<<dim3(24, 33), 256, 0, stream>>>(normbuf, w1_t, 3072, 768, 4112,
                                                             nullptr, midbuf, ff_b1 + i * 3072, nullptr);
        transpose_cast<<<dim3(96, 24), 256, 0, stream>>>(ff_w2 + (size_t)i * 3072 * 768, w2_t, 3072, 768);
        gemm64<6><<<dim3(12, 33), 256, 0, stream>>>(midbuf, w2_t, 768, 3072, 4112, xbuf, ff_b2 + i * 768);
    }

    // ---- head
    head_kernel<<<dim3(16, 4), 256, 0, stream>>>(xbuf, head_ln_g, head_ln_b, head_w, head_b, out);
}